// Round 3
// baseline (126.343 us; speedup 1.0000x reference)
//
#include <hip/hip_runtime.h>

#define DM 2048
#define NG 64
#define TPB 64          // tokens per block = lanes per wave
#define WK 128          // k-window
#define NQ (WK / 4)     // 32 quads per window
#define NWIN (DM / WK)  // 16
#define EPSV 1e-8f

typedef __attribute__((ext_vector_type(4))) float f32x4;

__device__ __forceinline__ void stage16(const float* gsrc, float* ldst) {
  __builtin_amdgcn_global_load_lds(
      (const __attribute__((address_space(1))) unsigned int*)gsrc,
      (__attribute__((address_space(3))) unsigned int*)ldst, 16, 0, 0);
}

// One block = 64 tokens, 8 waves; wave w computes groups [8w, 8w+8) over full K.
// x window LDS-staged (XOR-swizzled source, per-lane reads); W window LDS-staged
// (linear, wave-uniform broadcast reads). Fused softmax + top-8 epilogue.
__global__ __launch_bounds__(512, 1) void moe_router(
    const float* __restrict__ x, const float* __restrict__ W,
    float* __restrict__ out, int mtok)
{
  __shared__ float xs[2][TPB * WK];   // 2 x 32 KB
  __shared__ float wsh[2][NG * WK];   // 2 x 32 KB
  __shared__ float lbuf[TPB][NG];     // 16 KB

  const int tid  = threadIdx.x;
  const int lane = tid & 63;
  const int wid  = tid >> 6;          // 0..7
  const int g0   = wid << 3;
  const int tok0 = blockIdx.x * TPB;

  // stage window win -> buffer b. 2048 16B-slots each for x and W; 4 per thread.
  auto stage = [&](int win, int b) {
    const int k0 = win * WK;
#pragma unroll
    for (int i = 0; i < 4; ++i) {
      int idx = i * 512 + tid;        // slot = r*32 + q
      int r = idx >> 5;               // token row 0..63
      int q = idx & 31;               // dest quad in row
      int sq = q ^ (r & 31);          // swizzled source quad (involution)
      stage16(x + (size_t)(tok0 + r) * DM + k0 + (sq << 2), &xs[b][0] + (idx << 2));
    }
#pragma unroll
    for (int i = 0; i < 4; ++i) {
      int idx = i * 512 + tid;        // slot = g*32 + q, linear (broadcast reads)
      int g = idx >> 5;
      int q = idx & 31;
      stage16(W + (size_t)g * DM + k0 + (q << 2), &wsh[b][0] + (idx << 2));
    }
  };

  float acc[8] = {0.f, 0.f, 0.f, 0.f, 0.f, 0.f, 0.f, 0.f};

  stage(0, 0);
  __syncthreads();

  const int sz = lane & 31;
#pragma unroll 1
  for (int win = 0; win < NWIN; ++win) {
    const int b = win & 1;
    if (win + 1 < NWIN) stage(win + 1, b ^ 1);
    const float* xb = &xs[b][lane * WK];
#pragma unroll
    for (int kq = 0; kq < NQ; ++kq) {
      f32x4 xv = *(const f32x4*)(xb + ((kq ^ sz) << 2));
#pragma unroll
      for (int j = 0; j < 8; ++j) {
        f32x4 wv = *(const f32x4*)&wsh[b][(g0 + j) * WK + (kq << 2)];  // uniform -> broadcast
        acc[j] += xv.x * wv.x;
        acc[j] += xv.y * wv.y;
        acc[j] += xv.z * wv.z;
        acc[j] += xv.w * wv.w;
      }
    }
    __syncthreads();
  }

  // logits -> LDS, rotate-swizzled: lbuf[t][(g + t) & 63]
#pragma unroll
  for (int j = 0; j < 8; ++j)
    lbuf[lane][(g0 + j + lane) & 63] = acc[j];
  __syncthreads();

  // ---- epilogue: 8 lanes per token (validated round-2 math) ----
  const int tok = tid >> 3;           // 0..63
  const int l8  = tid & 7;

  float l[8];
#pragma unroll
  for (int j = 0; j < 8; ++j)
    l[j] = lbuf[tok][((l8 << 3) + j + tok) & 63];

  float m = l[0];
#pragma unroll
  for (int j = 1; j < 8; ++j) m = fmaxf(m, l[j]);
#pragma unroll
  for (int msk = 1; msk < 8; msk <<= 1) m = fmaxf(m, __shfl_xor(m, msk));

  float e[8];
  float sum = 0.f;
#pragma unroll
  for (int j = 0; j < 8; ++j) { e[j] = __expf(l[j] - m); sum += e[j]; }
#pragma unroll
  for (int msk = 1; msk < 8; msk <<= 1) sum += __shfl_xor(sum, msk);

  unsigned taken = 0;
  float esel = 0.f;
  for (int p = 0; p < 8; ++p) {
    float bv = -1.f;
    int bi = 127;
#pragma unroll
    for (int j = 0; j < 8; ++j) {
      bool avail = !((taken >> j) & 1u);
      float vv = e[j];
      int g = (l8 << 3) + j;
      bool better = avail && (vv > bv || (vv == bv && g < bi));
      bv = better ? vv : bv;
      bi = better ? g : bi;
    }
#pragma unroll
    for (int msk = 1; msk < 8; msk <<= 1) {
      float ov = __shfl_xor(bv, msk);
      int oi = __shfl_xor(bi, msk);
      bool better = (ov > bv) || (ov == bv && oi < bi);
      bv = better ? ov : bv;
      bi = better ? oi : bi;
    }
    esel += bv;
    if ((bi >> 3) == l8) taken |= 1u << (bi & 7);
  }

  const float inv = 1.f / sum;
  const float rsc = 1.f / (esel + EPSV * sum);
  const size_t MN = (size_t)mtok * NG;
  const size_t base = (size_t)(tok0 + tok) * NG + (l8 << 3);

  f32x4 r0, r1, m0, m1, s0, s1;
#pragma unroll
  for (int j = 0; j < 4; ++j) {
    float bitL = ((taken >> j) & 1u) ? 1.f : 0.f;
    float bitH = ((taken >> (j + 4)) & 1u) ? 1.f : 0.f;
    s0[j] = e[j] * inv;      s1[j] = e[j + 4] * inv;
    m0[j] = bitL;            m1[j] = bitH;
    r0[j] = bitL * e[j] * rsc;
    r1[j] = bitH * e[j + 4] * rsc;
  }
  *(f32x4*)&out[base]              = r0;
  *(f32x4*)&out[base + 4]          = r1;
  *(f32x4*)&out[MN + base]         = m0;
  *(f32x4*)&out[MN + base + 4]     = m1;
  *(f32x4*)&out[2 * MN + base]     = s0;
  *(f32x4*)&out[2 * MN + base + 4] = s1;
}

extern "C" void kernel_launch(void* const* d_in, const int* in_sizes, int n_in,
                              void* d_out, int out_size, void* d_ws, size_t ws_size,
                              hipStream_t stream) {
  const float* x = (const float*)d_in[0];
  const float* W = (const float*)d_in[1];
  float* out = (float*)d_out;
  const int mtok = in_sizes[0] / DM;          // 16384
  dim3 grid(mtok / TPB), block(512);
  hipLaunchKernelGGL(moe_router, grid, block, 0, stream, x, W, out, mtok);
}